// Round 1
// baseline (1093.993 us; speedup 1.0000x reference)
//
#include <hip/hip_runtime.h>
#include <math.h>

// Problem constants (from reference)
#define TT 2048
#define BB 512
#define II 11
#define HH 33
#define NL 3
#define OO 18
#define HSLOT 48          // halves per LDS vector slot (96 B, 16B-aligned slots)

typedef _Float16 h2 __attribute__((ext_vector_type(2)));
typedef _Float16 h8 __attribute__((ext_vector_type(8)));   // 16 B -> ds_read_b128

// fast sigmoid / tanh via v_exp_f32 + v_rcp_f32 (saturate correctly at +-inf)
__device__ __forceinline__ float sigm_f(float x) {
    float e = __expf(-x);
    return __builtin_amdgcn_rcpf(1.0f + e);
}
__device__ __forceinline__ float tanh_f(float x) {
    float e = __expf(2.0f * x);
    return 1.0f - 2.0f * __builtin_amdgcn_rcpf(e + 1.0f);
}

// lane<->lane^1 exchange via DPP quad_perm [1,0,3,2] (pure VALU, no LDS)
__device__ __forceinline__ float dppx1(float v) {
    return __int_as_float(__builtin_amdgcn_update_dpp(
        0, __float_as_int(v), 0xB1 /*quad_perm 1,0,3,2*/, 0xF, 0xF, true));
}

// guarded fp32->fp16 row-slice loads (zero-pad past rem)
__device__ __forceinline__ h8 gldh8(const float* p, int k0, int rem) {
    h8 v;
    #pragma unroll
    for (int i = 0; i < 8; ++i) v[i] = (_Float16)((k0 + i < rem) ? p[k0 + i] : 0.0f);
    return v;
}
__device__ __forceinline__ h2 gldh2(const float* p, int k0, int rem) {
    h2 v;
    v.x = (_Float16)((k0 + 0 < rem) ? p[k0 + 0] : 0.0f);
    v.y = (_Float16)((k0 + 1 < rem) ? p[k0 + 1] : 0.0f);
    return v;
}

// v_dot2_f32_f16: 2 MACs/op, fp32 accumulate
#define FD(a, p, q) a = __builtin_amdgcn_fdot2((p), (q), a, false)
// 4-way-interleaved quad: one h8 of the input vector against all 4 gate rows
#define DQ(v, W0, W1, W2, W3) do { \
    FD(a0, (v).s01, (W0).s01); FD(a1, (v).s01, (W1).s01); FD(a2, (v).s01, (W2).s01); FD(a3, (v).s01, (W3).s01); \
    FD(a0, (v).s23, (W0).s23); FD(a1, (v).s23, (W1).s23); FD(a2, (v).s23, (W2).s23); FD(a3, (v).s23, (W3).s23); \
    FD(a0, (v).s45, (W0).s45); FD(a1, (v).s45, (W1).s45); FD(a2, (v).s45, (W2).s45); FD(a3, (v).s45, (W3).s45); \
    FD(a0, (v).s67, (W0).s67); FD(a1, (v).s67, (W1).s67); FD(a2, (v).s67, (W2).s67); FD(a3, (v).s67, (W3).s67); \
} while (0)
#define D1Q(v) do { \
    FD(a0, (v), wi0t); FD(a1, (v), wi1t); FD(a2, (v), wi2t); FD(a3, (v), wi3t); \
} while (0)
#define D1QH(v) do { \
    FD(a0, (v), wh0t); FD(a1, (v), wh1t); FD(a2, (v), wh2t); FD(a3, (v), wh3t); \
} while (0)

// Layer-pipelined LSTM, TWO LANES PER UNIT (K-split + DPP pair reduce), fused MLP.
// grid = 512 blocks (one batch element each), block = 256 threads (4 waves)
//   -> 2048 waves total = 2 waves/SIMD; each SIMD hosts waves of DIFFERENT
//   blocks, so one block's barrier/LDS-latency/trans tail hides under the
//   other block's dot issue (the old 128-thread layout was 1 wave/SIMD and
//   ~70% of step time was exposed latency: 1234 cy/step vs ~330 cy of issue).
// tid < 198: unit u = tid>>1, half hf = tid&1. hf=0 owns k 0..15, hf=1 owns
//   k 16..33 of ALL 4 gate rows (input side + own-h side) => 72 fdot2/lane as
//   4 independent 18-deep chains (issue-bound), weights = 72 VGPRs/lane (fits
//   in arch VGPRs, no AGPR spill copies). Pair combine: 4 DPP(lane^1) adds;
//   transcendentals split across the pair (hf0: sigm(i),sigm(f); hf1:
//   tanh(g),sigm(o) -- same exp/rcp formulas, lane-constant A+B*rcp(exp(k*a)+1)),
//   2 DPP moves broadcast gates; both lanes compute identical c/h; hf0 writes.
// tid 200..210: x prefetchers (11 features), 2-deep software pipeline.
// LDS: ping-pong buf[2][4][HSLOT] halves; one barrier per superstep; peeled
// steady state with compile-time ping-pong.
__global__ __launch_bounds__(256, 2) void lstm_pipeline_kernel(
    const float* __restrict__ x,
    const float* __restrict__ Wih0, const float* __restrict__ Whh0,
    const float* __restrict__ bih0, const float* __restrict__ bhh0,
    const float* __restrict__ Wih1, const float* __restrict__ Whh1,
    const float* __restrict__ bih1, const float* __restrict__ bhh1,
    const float* __restrict__ Wih2, const float* __restrict__ Whh2,
    const float* __restrict__ bih2, const float* __restrict__ bhh2,
    const float* __restrict__ W1, const float* __restrict__ b1,
    const float* __restrict__ W2, const float* __restrict__ b2,
    float* __restrict__ hidden_out,   // [3, 512, 33]
    float* __restrict__ outp)         // [3, 512, 18]
{
    __shared__ __align__(16) _Float16 buf[2][NL + 1][HSLOT];
    __shared__ float hfin[NL][HH + 1];   // final h per layer (fp32, fused MLP)
    __shared__ float h1s[NL][4 * OO];    // MLP hidden

    const int tid = threadIdx.x;
    const int bg  = blockIdx.x;

    for (int i = tid; i < 2 * (NL + 1) * HSLOT; i += 256)
        ((_Float16*)buf)[i] = (_Float16)0.0f;

    const bool comp = (tid < 2 * 99);
    const int  u    = tid >> 1;                 // unit 0..98
    const int  hf   = tid & 1;                  // K-half: 0 -> k0..15, 1 -> k16..33
    const int  l    = (u < 33) ? 0 : (u < 66) ? 1 : 2;
    const int  j    = u - 33 * l;
    const int  koff = hf ? 16 : 0;

    const int  pi   = tid - 200;
    const bool pref = (pi >= 0) && (pi < II);
    const int  pic  = pref ? pi : 0;
    const float* xrow = x + (size_t)bg * TT * II + pic;

    // ---- per-lane weights: 4 gates x (input + own) x this lane's K-half ----
    h8 z8 = {0,0,0,0,0,0,0,0};
    h2 z2 = {(_Float16)0.0f, (_Float16)0.0f};
    h8 wi00=z8,wi01=z8, wi10=z8,wi11=z8, wi20=z8,wi21=z8, wi30=z8,wi31=z8;
    h2 wi0t=z2, wi1t=z2, wi2t=z2, wi3t=z2;      // k32..33 tail (hf=1 only)
    h8 wh00=z8,wh01=z8, wh10=z8,wh11=z8, wh20=z8,wh21=z8, wh30=z8,wh31=z8;
    h2 wh0t=z2, wh1t=z2, wh2t=z2, wh3t=z2;
    float b0 = 0.0f, b1v = 0.0f, b2v = 0.0f, b3v = 0.0f;   // bias on hf=0 only

    if (comp) {
        if (!hf) {
            const float* bip = (l == 0) ? bih0 : (l == 1) ? bih1 : bih2;
            const float* bhp = (l == 0) ? bhh0 : (l == 1) ? bhh1 : bhh2;
            b0  = bip[0 * HH + j] + bhp[0 * HH + j];
            b1v = bip[1 * HH + j] + bhp[1 * HH + j];
            b2v = bip[2 * HH + j] + bhp[2 * HH + j];
            b3v = bip[3 * HH + j] + bhp[3 * HH + j];
        }
        const float* Wi = (l == 0) ? Wih0 : (l == 1) ? Wih1 : Wih2;
        const float* Wh = (l == 0) ? Whh0 : (l == 1) ? Whh1 : Whh2;
        const int kin = (l == 0) ? II : HH;
        const float* r0 = Wi + (0 * HH + j) * kin;
        const float* r1 = Wi + (1 * HH + j) * kin;
        const float* r2 = Wi + (2 * HH + j) * kin;
        const float* r3 = Wi + (3 * HH + j) * kin;
        wi00 = gldh8(r0, koff, kin); wi01 = gldh8(r0, koff + 8, kin);
        wi10 = gldh8(r1, koff, kin); wi11 = gldh8(r1, koff + 8, kin);
        wi20 = gldh8(r2, koff, kin); wi21 = gldh8(r2, koff + 8, kin);
        wi30 = gldh8(r3, koff, kin); wi31 = gldh8(r3, koff + 8, kin);
        if (hf) {
            wi0t = gldh2(r0, 32, kin); wi1t = gldh2(r1, 32, kin);
            wi2t = gldh2(r2, 32, kin); wi3t = gldh2(r3, 32, kin);
        }
        const float* s0p = Wh + (0 * HH + j) * HH;
        const float* s1p = Wh + (1 * HH + j) * HH;
        const float* s2p = Wh + (2 * HH + j) * HH;
        const float* s3p = Wh + (3 * HH + j) * HH;
        wh00 = gldh8(s0p, koff, HH); wh01 = gldh8(s0p, koff + 8, HH);
        wh10 = gldh8(s1p, koff, HH); wh11 = gldh8(s1p, koff + 8, HH);
        wh20 = gldh8(s2p, koff, HH); wh21 = gldh8(s2p, koff + 8, HH);
        wh30 = gldh8(s3p, koff, HH); wh31 = gldh8(s3p, koff + 8, HH);
        if (hf) {
            wh0t = gldh2(s0p, 32, HH); wh1t = gldh2(s1p, 32, HH);
            wh2t = gldh2(s2p, 32, HH); wh3t = gldh2(s3p, 32, HH);
        }
    }

    // lane-constant unified nonlinearity coefs: xg = AX + BX * rcp(exp(kX*a)+1)
    //   hf=0: sigm(a0) -> kX=-1, AX=0, BX=+1      (gate i)
    //   hf=1: tanh(a2) -> kX=+2, AX=1, BX=-2      (gate g)
    const float kX = hf ? 2.0f : -1.0f;
    const float AX = hf ? 1.0f : 0.0f;
    const float BX = hf ? -2.0f : 1.0f;

    __syncthreads();
    float v_next = 0.0f, v_next2 = 0.0f;
    if (pref) {
        buf[0][0][pi] = (_Float16)xrow[0];
        v_next  = xrow[II];
        v_next2 = xrow[2 * II];
    }
    __syncthreads();

    float c = 0.0f;

    // hoisted ping-pong pointers (compile-time selected in peeled steps)
    const _Float16* rin[2]  = { &buf[0][l][0],     &buf[1][l][0] };      // input vec
    const _Float16* rown[2] = { &buf[0][l + 1][0], &buf[1][l + 1][0] };  // own-h vec
    _Float16*       wrp[2]  = { &buf[0][l + 1][j], &buf[1][l + 1][j] };
    _Float16*       pxp[2]  = { &buf[0][0][pic],   &buf[1][0][pic] };

    // one superstep; all bool/int args are compile-time constants at call sites
    auto step = [&](int s, int rp, bool check, bool out, bool xload, bool xstore)
        __attribute__((always_inline)) {
        const int wp = rp ^ 1;
        if (pref) {
            if (xstore) *pxp[wp] = (_Float16)v_next;
            v_next = v_next2;
            if (xload) v_next2 = xrow[(size_t)(s + 3) * II];
        }
        const bool active = check ? (comp && (s >= l) && (s - l < TT)) : comp;
        if (active) {
            const _Float16* ri = rin[rp];
            const _Float16* ro = rown[rp];
            // this lane's K-half of the two vectors (same-address broadcast
            // within each wave -> no bank conflicts)
            const h8 vi0 = *(const h8*)(ri + koff);
            const h8 vi1 = *(const h8*)(ri + koff + 8);
            const h2 vit = *(const h2*)(ri + 32);       // hf=0 lanes: weight=0
            const h8 vo0 = *(const h8*)(ro + koff);
            const h8 vo1 = *(const h8*)(ro + koff + 8);
            const h2 vot = *(const h2*)(ro + 32);

            // ---- 72 fdot2 as 4 independent 18-deep chains (issue-bound) ----
            float a0 = b0, a1 = b1v, a2 = b2v, a3 = b3v;
            DQ(vi0, wi00, wi10, wi20, wi30);
            DQ(vi1, wi01, wi11, wi21, wi31);
            DQ(vo0, wh00, wh10, wh20, wh30);
            DQ(vo1, wh01, wh11, wh21, wh31);
            D1Q(vit);
            D1QH(vot);

            // ---- pair reduce: full gate pre-activations on BOTH lanes ----
            a0 += dppx1(a0); a1 += dppx1(a1);
            a2 += dppx1(a2); a3 += dppx1(a3);

            // ---- split transcendentals across the pair ----
            const float aXv = hf ? a2 : a0;
            const float eX  = __expf(kX * aXv);
            const float rX  = __builtin_amdgcn_rcpf(1.0f + eX);
            const float xg  = __builtin_fmaf(BX, rX, AX);   // hf0: i  hf1: g
            const float yg  = sigm_f(hf ? a3 : a1);         // hf0: f  hf1: o

            const float xp = dppx1(xg);
            const float yp = dppx1(yg);
            const float ig = hf ? xp : xg;
            const float fg = hf ? yp : yg;
            const float gg = hf ? xg : xp;
            const float og = hf ? yg : yp;

            // identical on both lanes of the pair (keeps exec uniform)
            c = __builtin_fmaf(fg, c, ig * gg);
            const float hnew = og * tanh_f(c);

            if (!hf) {
                *wrp[wp] = (_Float16)hnew;
                if (out && (s - l == TT - 1)) {
                    hidden_out[((size_t)l * BB + bg) * HH + j] = hnew;
                    hfin[l][j] = hnew;
                }
            }
        }
        __syncthreads();
    };

    // prologue (pipeline fill, masked)
    step(0, 0, true, false, true, true);
    step(1, 1, true, false, true, true);
    // steady state: s = 2..2043 as constant-rp pairs (no checks, no outputs)
    for (int s = 2; s < TT - 4; s += 2) {
        step(s,     0, false, false, true, true);
        step(s + 1, 1, false, false, true, true);
    }
    // tail of steady state + epilogue (drain + final-h outputs)
    step(TT - 4, 0, false, false, true,  true);    // s=2044 (last x load)
    step(TT - 3, 1, false, false, false, true);    // s=2045
    step(TT - 2, 0, false, false, false, true);    // s=2046 (stores x[2047])
    step(TT - 1, 1, false, true,  false, false);   // s=2047: l0 writes hT
    step(TT,     0, true,  true,  false, false);   // s=2048: l1 writes hT
    step(TT + 1, 1, true,  true,  false, false);   // s=2049: l2 writes hT

    // ---- fused MLP head (hfin visible after the last step's barrier) ----
    // h1 = gelu_exact(hfin @ W1^T + b1) [3,72]; out = h1 @ W2^T + b2 [3,18]
    if (tid < 4 * OO) {                   // 72 threads x 3 layers
        #pragma unroll
        for (int ml = 0; ml < NL; ++ml) {
            float a = b1[tid];
            #pragma unroll
            for (int k = 0; k < HH; ++k) a += hfin[ml][k] * W1[tid * HH + k];
            h1s[ml][tid] = 0.5f * a * (1.0f + erff(a * 0.70710678118654752f));
        }
    }
    __syncthreads();
    if (tid < NL * OO) {                  // 54 threads
        const int ol = tid / OO, o = tid % OO;
        float a = b2[o];
        #pragma unroll
        for (int m = 0; m < 4 * OO; ++m) a += h1s[ol][m] * W2[o * (4 * OO) + m];
        outp[((size_t)ol * BB + bg) * OO + o] = a;
    }
}

extern "C" void kernel_launch(void* const* d_in, const int* in_sizes, int n_in,
                              void* d_out, int out_size, void* d_ws, size_t ws_size,
                              hipStream_t stream) {
    const float* x    = (const float*)d_in[0];
    const float* Wih0 = (const float*)d_in[1];
    const float* Whh0 = (const float*)d_in[2];
    const float* bih0 = (const float*)d_in[3];
    const float* bhh0 = (const float*)d_in[4];
    const float* Wih1 = (const float*)d_in[5];
    const float* Whh1 = (const float*)d_in[6];
    const float* bih1 = (const float*)d_in[7];
    const float* bhh1 = (const float*)d_in[8];
    const float* Wih2 = (const float*)d_in[9];
    const float* Whh2 = (const float*)d_in[10];
    const float* bih2 = (const float*)d_in[11];
    const float* bhh2 = (const float*)d_in[12];
    const float* W1   = (const float*)d_in[13];
    const float* b1   = (const float*)d_in[14];
    const float* W2   = (const float*)d_in[15];
    const float* b2   = (const float*)d_in[16];

    float* out    = (float*)d_out;                 // [3,512,18] = 27648 floats
    float* hidden = out + NL * BB * OO;            // [3,512,33] = 50688 floats

    lstm_pipeline_kernel<<<BB, 256, 0, stream>>>(
        x, Wih0, Whh0, bih0, bhh0, Wih1, Whh1, bih1, bhh1,
        Wih2, Whh2, bih2, bhh2, W1, b1, W2, b2, hidden, out);
}